// Round 3
// baseline (2996.699 us; speedup 1.0000x reference)
//
#include <hip/hip_runtime.h>
#include <math.h>

// ---------------------------------------------------------------------------
// B=64 graphs, NN=133 nodes. R-persist: R12's validated 11-kernel pipeline
// fused into ONE persistent kernel with a software grid barrier (device-scope
// atomics + threadfence), launched with plain hipLaunchKernelGGL.
// Round-0 lesson: hipLaunchCooperativeKernel silently failed in this harness
// (out stayed 0 => absmax = max|ref| = 0.379). This version depends on no
// cooperative API: residency is guaranteed by construction —
// __launch_bounds__(256,4) caps VGPR at 128 => 4 blocks/CU by regs; we launch
// 768 blocks = 3/CU (margin of 1 block/CU; LDS 8.7KB not binding).
// Barrier state is in workspace, zeroed by a tiny init kernel each call
// (workspace is re-poisoned between iterations). Spin has an escape hatch so
// any residency bug shows as a wrong answer, never a hang.
// Round-1 lesson: helper was declared after use -> compile fail; now inlined.
// Stages (inner loops byte-identical to R12):
//  S0 emb GEMM (399 tiles) + ballot prep    S1 gemm1 (532 tiles)
//  S2 spmm1<4,4>   S3 pool1<4,4>   S4 gemm2 (266)   S5 spmm2<2,8>
//  S6 pool2<2,8>   S7 gemm3 (266)  S8 spmm3<2,8>    S9 t4   S10 tail
// ---------------------------------------------------------------------------

#define NN 133
#define NPAIR 64
#define GRID 768
#define ROWS 8512              // 64*133

// ---------------- GEMM core: one 64x64 tile, prefetch-pipelined -------------
template<int VECA, int VECB, int RELU, int BIAS>
__device__ __forceinline__ void gemm_tile_core(
    const float* __restrict__ A, int lda, int K,
    const float* __restrict__ W, int N,
    const float* __restrict__ bias,
    float* __restrict__ C, int ldc, int padN,
    int m0, int n0, float (*As)[68], float (*Bs)[68], int tid)
{
    const int la_m = tid >> 2, la_k = (tid & 3) * 4;   // A: 64 rows x 4 float4
    const int lb_k = tid >> 4, lb_n = (tid & 15) * 4;  // B: 16 k-rows x 16 f4
    const int tx = tid & 15, ty = tid >> 4;
    const int r = m0 + la_m;

    float pa[4], pb[4];
    if (VECA) {
        float4 v = *reinterpret_cast<const float4*>(A + (size_t)r * lda + la_k);
        pa[0] = v.x; pa[1] = v.y; pa[2] = v.z; pa[3] = v.w;
    } else {
#pragma unroll
        for (int j = 0; j < 4; ++j) {
            int gk = la_k + j;
            pa[j] = (gk < K) ? A[(size_t)r * lda + gk] : 0.f;
        }
    }
    if (VECB) {
        if (lb_k < K) {
            float4 v = *reinterpret_cast<const float4*>(
                W + (size_t)lb_k * N + n0 + lb_n);
            pb[0] = v.x; pb[1] = v.y; pb[2] = v.z; pb[3] = v.w;
        } else { pb[0] = pb[1] = pb[2] = pb[3] = 0.f; }
    } else {
#pragma unroll
        for (int j = 0; j < 4; ++j) {
            int gn = n0 + lb_n + j;
            pb[j] = (lb_k < K && gn < N) ? W[(size_t)lb_k * N + gn] : 0.f;
        }
    }

    float acc[4][4] = {};
    for (int k0 = 0; k0 < K; k0 += 16) {
        __syncthreads();
#pragma unroll
        for (int j = 0; j < 4; ++j) As[la_k + j][la_m] = pa[j];
        *reinterpret_cast<float4*>(&Bs[lb_k][lb_n]) =
            make_float4(pb[0], pb[1], pb[2], pb[3]);
        __syncthreads();
        const int kn = k0 + 16;
        if (kn < K) {   // prefetch next k-tile (overlaps FMA block)
            if (VECA) {
                float4 v = *reinterpret_cast<const float4*>(
                    A + (size_t)r * lda + kn + la_k);
                pa[0] = v.x; pa[1] = v.y; pa[2] = v.z; pa[3] = v.w;
            } else {
#pragma unroll
                for (int j = 0; j < 4; ++j) {
                    int gk = kn + la_k + j;
                    pa[j] = (gk < K) ? A[(size_t)r * lda + gk] : 0.f;
                }
            }
            int gk = kn + lb_k;
            if (VECB) {
                if (gk < K) {
                    float4 v = *reinterpret_cast<const float4*>(
                        W + (size_t)gk * N + n0 + lb_n);
                    pb[0] = v.x; pb[1] = v.y; pb[2] = v.z; pb[3] = v.w;
                } else { pb[0] = pb[1] = pb[2] = pb[3] = 0.f; }
            } else {
#pragma unroll
                for (int j = 0; j < 4; ++j) {
                    int gn = n0 + lb_n + j;
                    pb[j] = (gk < K && gn < N) ? W[(size_t)gk * N + gn] : 0.f;
                }
            }
        }
#pragma unroll
        for (int k = 0; k < 16; ++k) {
            float4 av = *reinterpret_cast<const float4*>(&As[k][ty * 4]);
            float4 bv = *reinterpret_cast<const float4*>(&Bs[k][tx * 4]);
            float a[4] = {av.x, av.y, av.z, av.w};
            float b[4] = {bv.x, bv.y, bv.z, bv.w};
#pragma unroll
            for (int i = 0; i < 4; ++i)
#pragma unroll
                for (int j = 0; j < 4; ++j)
                    acc[i][j] = fmaf(a[i], b[j], acc[i][j]);
        }
    }
#pragma unroll
    for (int i = 0; i < 4; ++i) {
        int gm = m0 + ty * 4 + i;
#pragma unroll
        for (int j = 0; j < 4; ++j) {
            int gn = n0 + tx * 4 + j;
            if (gn < padN) {
                float v = 0.f;
                if (gn < N) {
                    v = acc[i][j];
                    if (BIAS) v += bias[gn];
                    if (RELU) v = fmaxf(v, 0.f);
                }
                C[(size_t)gm * ldc + gn] = v;
            }
        }
    }
}

// -------- ballot prep: fwd lists front=a>1e-5, back=0<a<=1e-5 ---------------
__device__ __forceinline__ void prep_row(
    const float* __restrict__ adj, float2* __restrict__ pairs,
    int2* __restrict__ cnts, int r, int lane)
{
    const float* ar = adj + (size_t)r * NN;
    float2* pb = pairs + (size_t)r * NPAIR;
    const unsigned long long lt = (1ull << lane) - 1ull;
    int base0 = 0, base1 = 0;
#pragma unroll
    for (int s = 0; s < 3; ++s) {
        const int j = lane + 64 * s;
        const float a = (j < NN) ? ar[j] : 0.f;
        const bool f = a > 1e-5f;
        const bool g = (a > 0.f) && !f;
        const unsigned long long mf = __ballot(f);
        const unsigned long long mg = __ballot(g);
        if (f) pb[base0 + __popcll(mf & lt)] =
                   make_float2(a, __int_as_float(j));
        if (g) pb[(NPAIR - 1) - (base1 + __popcll(mg & lt))] =
                   make_float2(a, __int_as_float(j));
        base0 += __popcll(mf);
        base1 += __popcll(mg);
    }
    if (lane == 0) cnts[r] = make_int2(base0, base1);
}

// -------- spmm: one wave per row, GRP*64 cols; CH gather chains -------------
template<int GRP, int CH>
__device__ __forceinline__ void spmm_row(
    const float* __restrict__ t, int ld, int N,
    const float* __restrict__ bias,
    const float2* __restrict__ pairs, const int2* __restrict__ cnts,
    float* __restrict__ y, int r, int lane)
{
    const int b = r / NN;
    int  c[GRP], sc[GRP];
#pragma unroll
    for (int u = 0; u < GRP; ++u) {
        c[u] = u * 64 + lane;
        sc[u] = min(c[u], N - 1);               // clamp for safe loads
    }
    const float2* pb = pairs + (size_t)r * NPAIR;
    const float4* pq = reinterpret_cast<const float4*>(pb);
    const int2 cc = cnts[r];
    const float* tb = t + (size_t)b * NN * ld;

    float acc[CH][GRP];
#pragma unroll
    for (int h = 0; h < CH; ++h)
#pragma unroll
        for (int u = 0; u < GRP; ++u) acc[h][u] = 0.f;

    int q = 0;
    for (; q + CH <= cc.x; q += CH) {           // CH independent gather chains
        const float* rp[CH];
        float wv[CH];
#pragma unroll
        for (int h = 0; h < CH; h += 2) {
            float4 pp = pq[(q + h) >> 1];
            wv[h] = pp.x;     rp[h]     = tb + (size_t)__float_as_int(pp.y) * ld;
            wv[h + 1] = pp.z; rp[h + 1] = tb + (size_t)__float_as_int(pp.w) * ld;
        }
#pragma unroll
        for (int h = 0; h < CH; ++h)
#pragma unroll
            for (int u = 0; u < GRP; ++u)
                acc[h][u] = fmaf(wv[h], rp[h][sc[u]], acc[h][u]);
    }
    for (; q + 2 <= cc.x; q += 2) {
        float4 pp = pq[q >> 1];
        const float* r0 = tb + (size_t)__float_as_int(pp.y) * ld;
        const float* r1 = tb + (size_t)__float_as_int(pp.w) * ld;
#pragma unroll
        for (int u = 0; u < GRP; ++u) {
            acc[0][u] = fmaf(pp.x, r0[sc[u]], acc[0][u]);
            acc[1][u] = fmaf(pp.z, r1[sc[u]], acc[1][u]);
        }
    }
    if (q < cc.x) {
        float2 f = pb[q];
        const float* r0 = tb + (size_t)__float_as_int(f.y) * ld;
#pragma unroll
        for (int u = 0; u < GRP; ++u) acc[0][u] = fmaf(f.x, r0[sc[u]], acc[0][u]);
    }
    for (int v = 0; v < cc.y; ++v) {            // tiny-weight tail (spmm only)
        float2 f = pb[(NPAIR - 1) - v];
        const float* r0 = tb + (size_t)__float_as_int(f.y) * ld;
#pragma unroll
        for (int u = 0; u < GRP; ++u) acc[0][u] = fmaf(f.x, r0[sc[u]], acc[0][u]);
    }
#pragma unroll
    for (int u = 0; u < GRP; ++u) {
        if (c[u] < N) {
            float s = 0.f;
#pragma unroll
            for (int h = 0; h < CH; ++h) s += acc[h][u];
            y[(size_t)r * ld + c[u]] = fmaxf(s + bias[c[u]], 0.f);
        }
    }
}

// -------- pool: p[r,col] = max over front nbrs j of y[j,col] (y>=0) ---------
template<int GRP, int CH>
__device__ __forceinline__ void pool_row(
    const float* __restrict__ y, int ld, int N,
    const float2* __restrict__ pairs, const int2* __restrict__ cnts,
    float* __restrict__ p, int r, int lane)
{
    const int b = r / NN;
    int  c[GRP], sc[GRP];
#pragma unroll
    for (int u = 0; u < GRP; ++u) {
        c[u] = u * 64 + lane;
        sc[u] = min(c[u], N - 1);
    }
    const float2* pb = pairs + (size_t)r * NPAIR;
    const float4* pq = reinterpret_cast<const float4*>(pb);
    const int cx = cnts[r].x;
    const float* yb = y + (size_t)b * NN * ld;

    float m[CH][GRP];
#pragma unroll
    for (int h = 0; h < CH; ++h)
#pragma unroll
        for (int u = 0; u < GRP; ++u) m[h][u] = 0.f;

    int q = 0;
    for (; q + CH <= cx; q += CH) {
        const float* rp[CH];
#pragma unroll
        for (int h = 0; h < CH; h += 2) {
            float4 pp = pq[(q + h) >> 1];
            rp[h]     = yb + (size_t)__float_as_int(pp.y) * ld;
            rp[h + 1] = yb + (size_t)__float_as_int(pp.w) * ld;
        }
#pragma unroll
        for (int h = 0; h < CH; ++h)
#pragma unroll
            for (int u = 0; u < GRP; ++u)
                m[h][u] = fmaxf(m[h][u], rp[h][sc[u]]);
    }
    for (; q + 2 <= cx; q += 2) {
        float4 pp = pq[q >> 1];
        const float* r0 = yb + (size_t)__float_as_int(pp.y) * ld;
        const float* r1 = yb + (size_t)__float_as_int(pp.w) * ld;
#pragma unroll
        for (int u = 0; u < GRP; ++u) {
            m[0][u] = fmaxf(m[0][u], r0[sc[u]]);
            m[1][u] = fmaxf(m[1][u], r1[sc[u]]);
        }
    }
    if (q < cx) {
        const float* r0 = yb + (size_t)__float_as_int(pb[q].y) * ld;
#pragma unroll
        for (int u = 0; u < GRP; ++u) m[0][u] = fmaxf(m[0][u], r0[sc[u]]);
    }
#pragma unroll
    for (int u = 0; u < GRP; ++u) {
        if (c[u] < N) {
            float s = 0.f;
#pragma unroll
            for (int h = 0; h < CH; ++h) s = fmaxf(s, m[h][u]);
            p[(size_t)r * ld + c[u]] = s;
        }
    }
}

// -------- t4: t4[r] = dot(pool3(y3)[r,0:75], gc4_w), one wave per row -------
__device__ __forceinline__ void t4_row(
    const float* __restrict__ y3,   // ld 76, 75 valid cols
    const float2* __restrict__ pairs, const int2* __restrict__ cnts,
    const float* __restrict__ gc4_w,
    float* __restrict__ t4, int r, int lane)
{
    const int b = r / NN;
    const float* yb = y3 + (size_t)b * NN * 76;
    const float2* pb = pairs + (size_t)r * NPAIR;
    const float4* pq = reinterpret_cast<const float4*>(pb);
    const int cx = cnts[r].x;
    const float gw0 = gc4_w[lane];                       // lane<=63<75 valid
    const float gw1 = (lane < 11) ? gc4_w[64 + lane] : 0.f;
    const int c2 = 64 + min(lane, 10);                   // safe 2nd col

    float m0a = 0.f, m1a = 0.f, m0b = 0.f, m1b = 0.f;
    float m0c = 0.f, m1c = 0.f, m0d = 0.f, m1d = 0.f;
    int q = 0;
    for (; q + 4 <= cx; q += 4) {               // 4 independent gather chains
        float4 pA = pq[q >> 1], pB = pq[(q >> 1) + 1];
        const float* r0 = yb + (size_t)__float_as_int(pA.y) * 76;
        const float* r1 = yb + (size_t)__float_as_int(pA.w) * 76;
        const float* r2 = yb + (size_t)__float_as_int(pB.y) * 76;
        const float* r3 = yb + (size_t)__float_as_int(pB.w) * 76;
        m0a = fmaxf(m0a, r0[lane]); m1a = fmaxf(m1a, r0[c2]);
        m0b = fmaxf(m0b, r1[lane]); m1b = fmaxf(m1b, r1[c2]);
        m0c = fmaxf(m0c, r2[lane]); m1c = fmaxf(m1c, r2[c2]);
        m0d = fmaxf(m0d, r3[lane]); m1d = fmaxf(m1d, r3[c2]);
    }
    for (; q < cx; ++q) {
        const float* r0 = yb + (size_t)__float_as_int(pb[q].y) * 76;
        m0a = fmaxf(m0a, r0[lane]); m1a = fmaxf(m1a, r0[c2]);
    }
    float m0 = fmaxf(fmaxf(m0a, m0b), fmaxf(m0c, m0d));
    float m1 = fmaxf(fmaxf(m1a, m1b), fmaxf(m1c, m1d));
    float v = m0 * gw0 + m1 * gw1;
#pragma unroll
    for (int off = 32; off; off >>= 1) v += __shfl_xor(v, off, 64);
    if (lane == 0) t4[r] = v;
}

// -------- software grid barrier (device-scope, persistent kernel) -----------
// bar[0]=arrival count, bar[32]=generation (separate 128B lines).
// All threads release-fence before arriving; thread0 does a device-scope
// ACQ_REL add (flushes this block's stores device-wide), last arriver bumps
// gen with RELEASE; waiters ACQUIRE-load gen; all threads re-fence after the
// barrier so subsequent loads cannot be hoisted and see fresh data.
// Escape hatch turns any residency bug into a visible wrong answer, not a hang.
__device__ __forceinline__ void gbar(unsigned* bar)
{
    __threadfence();                 // release (all threads)
    __syncthreads();
    if (threadIdx.x == 0) {
        unsigned* cnt = bar;
        unsigned* gen = bar + 32;
        unsigned g = __hip_atomic_load(gen, __ATOMIC_RELAXED,
                                       __HIP_MEMORY_SCOPE_AGENT);
        unsigned my = __hip_atomic_fetch_add(cnt, 1u, __ATOMIC_ACQ_REL,
                                             __HIP_MEMORY_SCOPE_AGENT);
        if (my == (unsigned)(gridDim.x - 1)) {
            __hip_atomic_store(cnt, 0u, __ATOMIC_RELAXED,
                               __HIP_MEMORY_SCOPE_AGENT);
            __hip_atomic_fetch_add(gen, 1u, __ATOMIC_RELEASE,
                                   __HIP_MEMORY_SCOPE_AGENT);
        } else {
            unsigned spins = 0;
            while (__hip_atomic_load(gen, __ATOMIC_ACQUIRE,
                                     __HIP_MEMORY_SCOPE_AGENT) == g) {
                __builtin_amdgcn_s_sleep(4);
                if (++spins > (1u << 24)) break;   // failsafe: no hang
            }
        }
    }
    __syncthreads();
    __threadfence();                 // acquire (all threads)
}

__global__ void init_bar_k(unsigned* bar)
{
    if (threadIdx.x < 64) bar[threadIdx.x] = 0u;
}

// --------------------------- the fused pipeline -----------------------------
struct Params {
    const float *x, *adj, *emb_w, *emb_b, *gc1_w, *gc1_b, *gc2_w, *gc2_b,
                *gc3_w, *gc3_b, *gc4_w, *gc4_b, *fc1_w, *fc1_b, *fin_w, *fin_b;
    float2* pairs;
    int2*   cnts;
    float  *bA, *bB, *bC, *t4;
    unsigned* bar;
    float*  out;
};

__global__ __launch_bounds__(256, 4)
void mega_k(Params P)
{
    __shared__ float As[16][68];
    __shared__ float Bs[16][68];
    const int tid  = threadIdx.x;
    const int bid  = blockIdx.x;
    const int NB   = gridDim.x;
    const int wave = tid >> 6, lane = tid & 63;
    const int rw   = bid * 4 + wave;            // row-wave id
    const int RW   = NB * 4;                    // row-waves per pass

    // S0: emb GEMM (399 tiles -> bC=h0 ld152) + ballot prep (2128 groups)
    for (int vb = bid; vb < 399 + 2128; vb += NB) {
        if (vb < 399) {
            gemm_tile_core<0, 0, 1, 1>(
                P.x, 75, 75, P.emb_w, 150, P.emb_b, P.bC, 152, 152,
                (vb / 3) * 64, (vb % 3) * 64, As, Bs, tid);
        } else {
            prep_row(P.adj, P.pairs, P.cnts, (vb - 399) * 4 + wave, lane);
        }
    }
    gbar(P.bar);
    // S1: t1 = h0 @ gc1_w -> bA ld 256 (532 tiles)
    for (int t = bid; t < 532; t += NB)
        gemm_tile_core<1, 1, 0, 0>(
            P.bC, 152, 150, P.gc1_w, 256, nullptr, P.bA, 256, 256,
            (t / 4) * 64, (t % 4) * 64, As, Bs, tid);
    gbar(P.bar);
    // S2: y1 -> bB
    for (int r = rw; r < ROWS; r += RW)
        spmm_row<4, 4>(P.bA, 256, 256, P.gc1_b, P.pairs, P.cnts, P.bB, r, lane);
    gbar(P.bar);
    // S3: p1 -> bC
    for (int r = rw; r < ROWS; r += RW)
        pool_row<4, 4>(P.bB, 256, 256, P.pairs, P.cnts, P.bC, r, lane);
    gbar(P.bar);
    // S4: t2 = p1 @ gc2_w -> bA ld 128 (266 tiles)
    for (int t = bid; t < 266; t += NB)
        gemm_tile_core<1, 1, 0, 0>(
            P.bC, 256, 256, P.gc2_w, 128, nullptr, P.bA, 128, 128,
            (t / 2) * 64, (t % 2) * 64, As, Bs, tid);
    gbar(P.bar);
    // S5: y2 -> bB
    for (int r = rw; r < ROWS; r += RW)
        spmm_row<2, 8>(P.bA, 128, 128, P.gc2_b, P.pairs, P.cnts, P.bB, r, lane);
    gbar(P.bar);
    // S6: p2 -> bC
    for (int r = rw; r < ROWS; r += RW)
        pool_row<2, 8>(P.bB, 128, 128, P.pairs, P.cnts, P.bC, r, lane);
    gbar(P.bar);
    // S7: t3 = p2 @ gc3_w -> bA ld 76 (padN=76 zero-fills col 75; 266 tiles)
    for (int t = bid; t < 266; t += NB)
        gemm_tile_core<1, 0, 0, 0>(
            P.bC, 128, 128, P.gc3_w, 75, nullptr, P.bA, 76, 76,
            (t / 2) * 64, (t % 2) * 64, As, Bs, tid);
    gbar(P.bar);
    // S8: y3 -> bB (N=75)
    for (int r = rw; r < ROWS; r += RW)
        spmm_row<2, 8>(P.bA, 76, 75, P.gc3_b, P.pairs, P.cnts, P.bB, r, lane);
    gbar(P.bar);
    // S9: t4[r] = pool3(y3)[r] . gc4_w
    for (int r = rw; r < ROWS; r += RW)
        t4_row(P.bB, P.pairs, P.cnts, P.gc4_w, P.t4, r, lane);
    gbar(P.bar);
    // S10: tail — y4 = relu(A@t4+b4); fc1; fin; sigmoid (first 64 blocks)
    if (bid < 64) {
        const int b = bid;
        float* t4S = &As[0][0];       // overlay: 1088 floats >= 269 needed
        float* y4S = t4S + NN;
        float* rS  = y4S + NN;
        if (tid < NN) t4S[tid] = P.t4[b * NN + tid];
        __syncthreads();
        if (tid < NN) {
            const float2* pb = P.pairs + ((size_t)b * NN + tid) * NPAIR;
            int2 c = P.cnts[b * NN + tid];
            float s = P.gc4_b[0];
            for (int q = 0; q < c.x; ++q) {
                float2 f = pb[q];
                s = fmaf(f.x, t4S[__float_as_int(f.y)], s);
            }
            for (int q = 0; q < c.y; ++q) {
                float2 f = pb[(NPAIR - 1) - q];
                s = fmaf(f.x, t4S[__float_as_int(f.y)], s);
            }
            y4S[tid] = fmaxf(s, 0.f);
        }
        __syncthreads();
        if (tid < 3) {
            float s = P.fc1_b[tid];
            for (int j = 0; j < 132; ++j)
                s = fmaf(y4S[1 + j], P.fc1_w[j * 3 + tid], s);
            rS[tid] = s;
        }
        __syncthreads();
        if (tid == 0) {
            float z = P.fin_b[0] + y4S[0] * P.fin_w[0] + rS[0] * P.fin_w[1]
                    + rS[1] * P.fin_w[2] + rS[2] * P.fin_w[3];
            P.out[b] = 1.f / (1.f + expf(-z));
        }
    }
}

extern "C" void kernel_launch(void* const* d_in, const int* in_sizes, int n_in,
                              void* d_out, int out_size, void* d_ws, size_t ws_size,
                              hipStream_t stream)
{
    // ws: pairs 4.36MB | cnts 68KB | bA 8.72MB | bB 8.72MB | bC 8.72MB | t4 | bar
    const long MR = 64L * NN;                    // 8512
    float2* pairs = (float2*)d_ws;
    int2*   cnts  = (int2*)(pairs + MR * NPAIR);
    float*  bA    = (float*)(cnts + MR);
    float*  bB    = bA + MR * 256;
    float*  bC    = bB + MR * 256;
    float*  t4    = bC + MR * 256;               // 8512 floats
    unsigned* bar = (unsigned*)(t4 + MR);        // 64 u32 (2 cachelines used)

    Params hp;
    hp.x     = (const float*)d_in[0];
    hp.adj   = (const float*)d_in[1];
    hp.emb_w = (const float*)d_in[2];
    hp.emb_b = (const float*)d_in[3];
    hp.gc1_w = (const float*)d_in[4];
    hp.gc1_b = (const float*)d_in[5];
    hp.gc2_w = (const float*)d_in[6];
    hp.gc2_b = (const float*)d_in[7];
    hp.gc3_w = (const float*)d_in[8];
    hp.gc3_b = (const float*)d_in[9];
    hp.gc4_w = (const float*)d_in[10];
    hp.gc4_b = (const float*)d_in[11];
    hp.fc1_w = (const float*)d_in[12];
    hp.fc1_b = (const float*)d_in[13];
    hp.fin_w = (const float*)d_in[14];
    hp.fin_b = (const float*)d_in[15];
    hp.pairs = pairs; hp.cnts = cnts;
    hp.bA = bA; hp.bB = bB; hp.bC = bC; hp.t4 = t4;
    hp.bar = bar;
    hp.out   = (float*)d_out;

    hipLaunchKernelGGL(init_bar_k, dim3(1), dim3(64), 0, stream, bar);
    hipLaunchKernelGGL(mega_k, dim3(GRID), dim3(256), 0, stream, hp);
}

// Round 4
// 436.863 us; speedup vs baseline: 6.8596x; 6.8596x over previous
//
#include <hip/hip_runtime.h>
#include <math.h>

// ---------------------------------------------------------------------------
// B=64 graphs, NN=133 nodes. R-graphblock: ONE BLOCK PER GRAPH (64 blocks x
// 1024 threads = 16 waves), zero cross-block sync. Round-2 evidence:
// VALUBusy=1.13% over 2975us => real compute ~34us; 10 SW grid barriers cost
// ~294us each (768 serialized device-scope atomics + poll flood + fence-led
// 791MB HBM refetch). The op's dependency structure is per-graph (spmm/pool
// mix rows, gemm mixes cols, nothing crosses graphs), so per-graph blocks
// turn every grid barrier into __syncthreads().
//  - pairs/cnts ballot lists live entirely in LDS (68KB), never hit global.
//  - all activation buffers use uniform 256-float row slots => per-graph
//    regions are disjoint across bA/bB/bC at every stage (no cross-block
//    hazard even though blocks run unsynchronized).
//  - GEMM: 9-rows-per-wave register blocking, W row broadcast per k
//    (k-order identical to R12 => bit-identical output expected).
//  - sparse stages: same validated gather-chain loops, wave-per-row.
// Stage chain (11 __syncthreads):
//  prep+emb | gemm1 | spmm1 | pool1 | gemm2 | spmm2 | pool2 | gemm3 |
//  spmm3 | t4 | tail
// ---------------------------------------------------------------------------

#define NN 133
#define NPAIR 64
#define LD 256                 // uniform row slot (floats) for bA/bB/bC
#define NW 16                  // waves per block (1024 threads)

struct Params {
    const float *x, *adj, *emb_w, *emb_b, *gc1_w, *gc1_b, *gc2_w, *gc2_b,
                *gc3_w, *gc3_b, *gc4_w, *gc4_b, *fc1_w, *fc1_b, *fin_w, *fin_b;
    float *bA, *bB, *bC;
    float *out;
};

// -------- GEMM: rows partitioned over waves, 8-9 rows/wave, reg-blocked -----
// C[r, c] = sum_k A[r,k] * W[k,c]  (+bias, relu optional); C ld = LD.
// Row partition: wave w owns rows [w*NN/16, (w+1)*NN/16) -> 8 or 9 rows.
// A loads are wave-uniform (broadcast); W row k is shared by all waves (L2).
// k-order matches R12's accumulation order => identical rounding.
template<int CHUNKS, int RELU, int BIAS>
__device__ __forceinline__ void gemm_rows(
    const float* __restrict__ A, int lda, int K,
    const float* __restrict__ W, int N, const float* __restrict__ bias,
    float* __restrict__ C, int wave, int lane)
{
    const int rbase = (wave * NN) >> 4;
    const int rcnt  = (((wave + 1) * NN) >> 4) - rbase;   // 8 or 9
    int co[CHUNKS]; bool cv[CHUNKS];
#pragma unroll
    for (int g = 0; g < CHUNKS; ++g) {
        int c = lane + 64 * g;
        cv[g] = (c < N);
        co[g] = min(c, N - 1);          // clamp: keep W loads in-bounds
    }
    float acc[9][CHUNKS];
#pragma unroll
    for (int i = 0; i < 9; ++i)
#pragma unroll
        for (int g = 0; g < CHUNKS; ++g) acc[i][g] = 0.f;

    const float* Ar[9];
#pragma unroll
    for (int i = 0; i < 9; ++i)
        Ar[i] = A + (size_t)(rbase + i) * lda;   // rbase+8 <= 132 always

    for (int k = 0; k < K; ++k) {
        float wv[CHUNKS];
#pragma unroll
        for (int g = 0; g < CHUNKS; ++g) wv[g] = W[(size_t)k * N + co[g]];
#pragma unroll
        for (int i = 0; i < 9; ++i) {
            const float a = Ar[i][k];
#pragma unroll
            for (int g = 0; g < CHUNKS; ++g)
                acc[i][g] = fmaf(a, wv[g], acc[i][g]);
        }
    }
#pragma unroll
    for (int i = 0; i < 9; ++i) {
        if (i < rcnt) {
            const int r = rbase + i;
#pragma unroll
            for (int g = 0; g < CHUNKS; ++g) {
                if (cv[g]) {
                    float v = acc[i][g];
                    if (BIAS) v += bias[co[g]];
                    if (RELU) v = fmaxf(v, 0.f);
                    C[(size_t)r * LD + lane + 64 * g] = v;
                }
            }
        }
    }
}

// -------- ballot prep into LDS: front=a>1e-5, back=0<a<=1e-5 ----------------
__device__ __forceinline__ void prep_row_l(
    const float* __restrict__ ar, float2* __restrict__ pb,
    int2* __restrict__ cS, int r, int lane)
{
    const unsigned long long lt = (1ull << lane) - 1ull;
    int base0 = 0, base1 = 0;
#pragma unroll
    for (int s = 0; s < 3; ++s) {
        const int j = lane + 64 * s;
        const float a = (j < NN) ? ar[j] : 0.f;
        const bool f = a > 1e-5f;
        const bool g = (a > 0.f) && !f;
        const unsigned long long mf = __ballot(f);
        const unsigned long long mg = __ballot(g);
        if (f) pb[base0 + __popcll(mf & lt)] =
                   make_float2(a, __int_as_float(j));
        if (g) pb[(NPAIR - 1) - (base1 + __popcll(mg & lt))] =
                   make_float2(a, __int_as_float(j));
        base0 += __popcll(mf);
        base1 += __popcll(mg);
    }
    if (lane == 0) cS[r] = make_int2(base0, base1);
}

// -------- spmm: one wave per row, GRP*64 cols, CH gather chains -------------
template<int GRP, int CH>
__device__ __forceinline__ void spmm_row_l(
    const float* __restrict__ tb, int N,     // graph base, ld LD
    const float* __restrict__ bias,
    const float2* __restrict__ pb, int2 cc,  // LDS pair row + counts
    float* __restrict__ yrow, int lane)      // out row base (ld LD)
{
    int c[GRP], sc[GRP];
#pragma unroll
    for (int u = 0; u < GRP; ++u) {
        c[u] = u * 64 + lane;
        sc[u] = min(c[u], N - 1);
    }
    const float4* pq = reinterpret_cast<const float4*>(pb);

    float acc[CH][GRP];
#pragma unroll
    for (int h = 0; h < CH; ++h)
#pragma unroll
        for (int u = 0; u < GRP; ++u) acc[h][u] = 0.f;

    int q = 0;
    for (; q + CH <= cc.x; q += CH) {
        const float* rp[CH];
        float wv[CH];
#pragma unroll
        for (int h = 0; h < CH; h += 2) {
            float4 pp = pq[(q + h) >> 1];
            wv[h] = pp.x;     rp[h]     = tb + (size_t)__float_as_int(pp.y) * LD;
            wv[h + 1] = pp.z; rp[h + 1] = tb + (size_t)__float_as_int(pp.w) * LD;
        }
#pragma unroll
        for (int h = 0; h < CH; ++h)
#pragma unroll
            for (int u = 0; u < GRP; ++u)
                acc[h][u] = fmaf(wv[h], rp[h][sc[u]], acc[h][u]);
    }
    for (; q + 2 <= cc.x; q += 2) {
        float4 pp = pq[q >> 1];
        const float* r0 = tb + (size_t)__float_as_int(pp.y) * LD;
        const float* r1 = tb + (size_t)__float_as_int(pp.w) * LD;
#pragma unroll
        for (int u = 0; u < GRP; ++u) {
            acc[0][u] = fmaf(pp.x, r0[sc[u]], acc[0][u]);
            acc[1][u] = fmaf(pp.z, r1[sc[u]], acc[1][u]);
        }
    }
    if (q < cc.x) {
        float2 f = pb[q];
        const float* r0 = tb + (size_t)__float_as_int(f.y) * LD;
#pragma unroll
        for (int u = 0; u < GRP; ++u) acc[0][u] = fmaf(f.x, r0[sc[u]], acc[0][u]);
    }
    for (int v = 0; v < cc.y; ++v) {            // tiny-weight tail (spmm only)
        float2 f = pb[(NPAIR - 1) - v];
        const float* r0 = tb + (size_t)__float_as_int(f.y) * LD;
#pragma unroll
        for (int u = 0; u < GRP; ++u) acc[0][u] = fmaf(f.x, r0[sc[u]], acc[0][u]);
    }
#pragma unroll
    for (int u = 0; u < GRP; ++u) {
        if (c[u] < N) {
            float s = 0.f;
#pragma unroll
            for (int h = 0; h < CH; ++h) s += acc[h][u];
            yrow[c[u]] = fmaxf(s + bias[c[u]], 0.f);
        }
    }
}

// -------- pool: p[col] = max over front nbrs j of y[j,col] (y>=0) -----------
template<int GRP, int CH>
__device__ __forceinline__ void pool_row_l(
    const float* __restrict__ yb, int N,
    const float2* __restrict__ pb, int cx,
    float* __restrict__ prow, int lane)
{
    int c[GRP], sc[GRP];
#pragma unroll
    for (int u = 0; u < GRP; ++u) {
        c[u] = u * 64 + lane;
        sc[u] = min(c[u], N - 1);
    }
    const float4* pq = reinterpret_cast<const float4*>(pb);

    float m[CH][GRP];
#pragma unroll
    for (int h = 0; h < CH; ++h)
#pragma unroll
        for (int u = 0; u < GRP; ++u) m[h][u] = 0.f;

    int q = 0;
    for (; q + CH <= cx; q += CH) {
        const float* rp[CH];
#pragma unroll
        for (int h = 0; h < CH; h += 2) {
            float4 pp = pq[(q + h) >> 1];
            rp[h]     = yb + (size_t)__float_as_int(pp.y) * LD;
            rp[h + 1] = yb + (size_t)__float_as_int(pp.w) * LD;
        }
#pragma unroll
        for (int h = 0; h < CH; ++h)
#pragma unroll
            for (int u = 0; u < GRP; ++u)
                m[h][u] = fmaxf(m[h][u], rp[h][sc[u]]);
    }
    for (; q + 2 <= cx; q += 2) {
        float4 pp = pq[q >> 1];
        const float* r0 = yb + (size_t)__float_as_int(pp.y) * LD;
        const float* r1 = yb + (size_t)__float_as_int(pp.w) * LD;
#pragma unroll
        for (int u = 0; u < GRP; ++u) {
            m[0][u] = fmaxf(m[0][u], r0[sc[u]]);
            m[1][u] = fmaxf(m[1][u], r1[sc[u]]);
        }
    }
    if (q < cx) {
        const float* r0 = yb + (size_t)__float_as_int(pb[q].y) * LD;
#pragma unroll
        for (int u = 0; u < GRP; ++u) m[0][u] = fmaxf(m[0][u], r0[sc[u]]);
    }
#pragma unroll
    for (int u = 0; u < GRP; ++u) {
        if (c[u] < N) {
            float s = 0.f;
#pragma unroll
            for (int h = 0; h < CH; ++h) s = fmaxf(s, m[h][u]);
            prow[c[u]] = s;
        }
    }
}

// -------- t4: t4S[r] = dot(pool3(y3)[r,0:75], gc4_w) ------------------------
__device__ __forceinline__ void t4_row_l(
    const float* __restrict__ yb,            // y3 graph base, ld LD
    const float2* __restrict__ pb, int cx,
    const float* __restrict__ gc4_w,
    float* __restrict__ t4S, int r, int lane)
{
    const float4* pq = reinterpret_cast<const float4*>(pb);
    const float gw0 = gc4_w[lane];                       // lane<=63<75 valid
    const float gw1 = (lane < 11) ? gc4_w[64 + lane] : 0.f;
    const int c2 = 64 + min(lane, 10);                   // safe 2nd col

    float m0a = 0.f, m1a = 0.f, m0b = 0.f, m1b = 0.f;
    float m0c = 0.f, m1c = 0.f, m0d = 0.f, m1d = 0.f;
    int q = 0;
    for (; q + 4 <= cx; q += 4) {
        float4 pA = pq[q >> 1], pB = pq[(q >> 1) + 1];
        const float* r0 = yb + (size_t)__float_as_int(pA.y) * LD;
        const float* r1 = yb + (size_t)__float_as_int(pA.w) * LD;
        const float* r2 = yb + (size_t)__float_as_int(pB.y) * LD;
        const float* r3 = yb + (size_t)__float_as_int(pB.w) * LD;
        m0a = fmaxf(m0a, r0[lane]); m1a = fmaxf(m1a, r0[c2]);
        m0b = fmaxf(m0b, r1[lane]); m1b = fmaxf(m1b, r1[c2]);
        m0c = fmaxf(m0c, r2[lane]); m1c = fmaxf(m1c, r2[c2]);
        m0d = fmaxf(m0d, r3[lane]); m1d = fmaxf(m1d, r3[c2]);
    }
    for (; q < cx; ++q) {
        const float* r0 = yb + (size_t)__float_as_int(pb[q].y) * LD;
        m0a = fmaxf(m0a, r0[lane]); m1a = fmaxf(m1a, r0[c2]);
    }
    float m0 = fmaxf(fmaxf(m0a, m0b), fmaxf(m0c, m0d));
    float m1 = fmaxf(fmaxf(m1a, m1b), fmaxf(m1c, m1d));
    float v = m0 * gw0 + m1 * gw1;
#pragma unroll
    for (int off = 32; off; off >>= 1) v += __shfl_xor(v, off, 64);
    if (lane == 0) t4S[r] = v;
}

// --------------------------- one block = one graph --------------------------
__global__ __launch_bounds__(1024, 1)
void graph_k(Params P)
{
    __shared__ __align__(16) float2 pairsS[NN][NPAIR];   // 68.1 KB
    __shared__ int2  cS[NN];
    __shared__ float t4S[NN];
    __shared__ float y4S[NN];
    __shared__ float rS[3];

    const int b    = blockIdx.x;
    const int tid  = threadIdx.x;
    const int wave = tid >> 6, lane = tid & 63;

    float* bAg = P.bA + (size_t)b * NN * LD;   // t1 / t2 / t3
    float* bBg = P.bB + (size_t)b * NN * LD;   // h0 / y1 / y2 / y3
    float* bCg = P.bC + (size_t)b * NN * LD;   // p1 / p2

    // S0: ballot prep (LDS) + emb GEMM h0 = relu(x@emb_w+b) -> bBg (150 cols)
    for (int r = wave; r < NN; r += NW)
        prep_row_l(P.adj + (size_t)(b * NN + r) * NN, pairsS[r], cS, r, lane);
    gemm_rows<3, 1, 1>(P.x + (size_t)b * NN * 75, 75, 75,
                       P.emb_w, 150, P.emb_b, bBg, wave, lane);
    __syncthreads();
    // S1: t1 = h0 @ gc1_w -> bAg (256 cols)
    gemm_rows<4, 0, 0>(bBg, LD, 150, P.gc1_w, 256, nullptr, bAg, wave, lane);
    __syncthreads();
    // S2: y1 = relu(spmm(t1)+b1) -> bBg
    for (int r = wave; r < NN; r += NW)
        spmm_row_l<4, 4>(bAg, 256, P.gc1_b, pairsS[r], cS[r],
                         bBg + (size_t)r * LD, lane);
    __syncthreads();
    // S3: p1 = pool(y1) -> bCg
    for (int r = wave; r < NN; r += NW)
        pool_row_l<4, 4>(bBg, 256, pairsS[r], cS[r].x,
                         bCg + (size_t)r * LD, lane);
    __syncthreads();
    // S4: t2 = p1 @ gc2_w -> bAg (128 cols)
    gemm_rows<2, 0, 0>(bCg, LD, 256, P.gc2_w, 128, nullptr, bAg, wave, lane);
    __syncthreads();
    // S5: y2 -> bBg
    for (int r = wave; r < NN; r += NW)
        spmm_row_l<2, 8>(bAg, 128, P.gc2_b, pairsS[r], cS[r],
                         bBg + (size_t)r * LD, lane);
    __syncthreads();
    // S6: p2 -> bCg
    for (int r = wave; r < NN; r += NW)
        pool_row_l<2, 8>(bBg, 128, pairsS[r], cS[r].x,
                         bCg + (size_t)r * LD, lane);
    __syncthreads();
    // S7: t3 = p2 @ gc3_w -> bAg (75 cols)
    gemm_rows<2, 0, 0>(bCg, LD, 128, P.gc3_w, 75, nullptr, bAg, wave, lane);
    __syncthreads();
    // S8: y3 -> bBg (N=75)
    for (int r = wave; r < NN; r += NW)
        spmm_row_l<2, 8>(bAg, 75, P.gc3_b, pairsS[r], cS[r],
                         bBg + (size_t)r * LD, lane);
    __syncthreads();
    // S9: t4S[r] = pool3(y3)[r] . gc4_w
    for (int r = wave; r < NN; r += NW)
        t4_row_l(bBg, pairsS[r], cS[r].x, P.gc4_w, t4S, r, lane);
    __syncthreads();
    // S10: tail — y4 = relu(A@t4+b4); fc1; fin; sigmoid
    if (tid < NN) {
        const float2* pb = pairsS[tid];
        int2 c = cS[tid];
        float s = P.gc4_b[0];
        for (int q = 0; q < c.x; ++q) {
            float2 f = pb[q];
            s = fmaf(f.x, t4S[__float_as_int(f.y)], s);
        }
        for (int q = 0; q < c.y; ++q) {
            float2 f = pb[(NPAIR - 1) - q];
            s = fmaf(f.x, t4S[__float_as_int(f.y)], s);
        }
        y4S[tid] = fmaxf(s, 0.f);
    }
    __syncthreads();
    if (tid < 3) {
        float s = P.fc1_b[tid];
        for (int j = 0; j < 132; ++j)
            s = fmaf(y4S[1 + j], P.fc1_w[j * 3 + tid], s);
        rS[tid] = s;
    }
    __syncthreads();
    if (tid == 0) {
        float z = P.fin_b[0] + y4S[0] * P.fin_w[0] + rS[0] * P.fin_w[1]
                + rS[1] * P.fin_w[2] + rS[2] * P.fin_w[3];
        P.out[b] = 1.f / (1.f + expf(-z));
    }
}

extern "C" void kernel_launch(void* const* d_in, const int* in_sizes, int n_in,
                              void* d_out, int out_size, void* d_ws, size_t ws_size,
                              hipStream_t stream)
{
    // ws: bA | bB | bC, each 8512 x 256 floats (8.72 MB). pairs/cnts in LDS.
    const size_t MR = (size_t)64 * NN;           // 8512 rows
    float* bA = (float*)d_ws;
    float* bB = bA + MR * LD;
    float* bC = bB + MR * LD;

    Params hp;
    hp.x     = (const float*)d_in[0];
    hp.adj   = (const float*)d_in[1];
    hp.emb_w = (const float*)d_in[2];
    hp.emb_b = (const float*)d_in[3];
    hp.gc1_w = (const float*)d_in[4];
    hp.gc1_b = (const float*)d_in[5];
    hp.gc2_w = (const float*)d_in[6];
    hp.gc2_b = (const float*)d_in[7];
    hp.gc3_w = (const float*)d_in[8];
    hp.gc3_b = (const float*)d_in[9];
    hp.gc4_w = (const float*)d_in[10];
    hp.gc4_b = (const float*)d_in[11];
    hp.fc1_w = (const float*)d_in[12];
    hp.fc1_b = (const float*)d_in[13];
    hp.fin_w = (const float*)d_in[14];
    hp.fin_b = (const float*)d_in[15];
    hp.bA = bA; hp.bB = bB; hp.bC = bC;
    hp.out = (float*)d_out;

    hipLaunchKernelGGL(graph_k, dim3(64), dim3(1024), 0, stream, hp);
}

// Round 5
// 295.877 us; speedup vs baseline: 10.1282x; 1.4765x over previous
//
#include <hip/hip_runtime.h>
#include <math.h>

// ---------------------------------------------------------------------------
// B=64 graphs, NN=133 nodes. R-ldsgemm: one block per graph (64 x 1024thr),
// round-3 structure (absmax 0.0, FETCH+WRITE 791->56MB) with the latency
// fixes round-3's counters demanded (VALUBusy 40% of active CUs => 60% stall
// from per-k wave-uniform A loads thrashing L1):
//  - ALL GEMM A-operands staged in LDS (81KB scratch region SCR): A-reads are
//    uniform ds_read broadcasts; h0 is written straight to LDS by emb GEMM
//    (never touches global); gemm2 runs two 128-col k-passes of p1.
//  - packed fp32 (v_pk_fma_f32 via ext_vector float2 + elementwise_fma)
//    halves GEMM VALU issue.
//  - gathers vectorized: spmm1/pool1 one float4/chain-row (global, L2-hot);
//    spmm2/pool2/spmm3 float2 from LDS (t2/t3/y2 staged in SCR).
// LDS: pairs 68.1KB + SCR 80.9KB + misc 2.1KB = 151.1KB (<160KB).
// Stage chain: x->SCR|prep ; emb->SCR(h0) ; gemm1->t1 g ; spmm1 g->g ;
// pool1 g->g ; gemm2 (2 LDS k-passes)->t2 LDS ; spmm2 LDS->y2 g ; stage y2 ;
// pool2 LDS->p2 g ; stage p2 ; gemm3->t3 LDS ; spmm3 LDS->y3 g ; t4 ; tail.
// ---------------------------------------------------------------------------

#define NN 133
#define NPAIR 64
#define NW 16

typedef float v2f __attribute__((ext_vector_type(2)));
typedef float v4f __attribute__((ext_vector_type(4)));

struct Params {
    const float *x, *adj, *emb_w, *emb_b, *gc1_w, *gc1_b, *gc2_w, *gc2_b,
                *gc3_w, *gc3_b, *gc4_w, *gc4_b, *fc1_w, *fc1_b, *fin_w, *fin_b;
    float *bA, *bB, *bC;
    float *out;
};

// -------- ballot prep into LDS: front=a>1e-5, back=0<a<=1e-5 ----------------
__device__ __forceinline__ void prep_row_l(
    const float* __restrict__ ar, float2* __restrict__ pb,
    int2* __restrict__ cS, int r, int lane)
{
    const unsigned long long lt = (1ull << lane) - 1ull;
    int base0 = 0, base1 = 0;
#pragma unroll
    for (int s = 0; s < 3; ++s) {
        const int j = lane + 64 * s;
        const float a = (j < NN) ? ar[j] : 0.f;
        const bool f = a > 1e-5f;
        const bool g = (a > 0.f) && !f;
        const unsigned long long mf = __ballot(f);
        const unsigned long long mg = __ballot(g);
        if (f) pb[base0 + __popcll(mf & lt)] =
                   make_float2(a, __int_as_float(j));
        if (g) pb[(NPAIR - 1) - (base1 + __popcll(mg & lt))] =
                   make_float2(a, __int_as_float(j));
        base0 += __popcll(mf);
        base1 += __popcll(mg);
    }
    if (lane == 0) cS[r] = make_int2(base0, base1);
}

// -------- GEMM accumulate: A in LDS (uniform broadcast), pk-fma columns -----
// cols: chunk g covers c = g*128 + 2*lane (float2); W reads clamped to
// (N-2)&~1 so OOB lanes read in-bounds garbage (discarded at store).
template<int CHUNKS>
__device__ __forceinline__ void gemm_acc(
    const float* __restrict__ A, int lda, int K, int kW0,
    const float* __restrict__ W, int N,
    v2f (&acc)[9][CHUNKS], int rbase, int lane)
{
    int co[CHUNKS];
#pragma unroll
    for (int g = 0; g < CHUNKS; ++g)
        co[g] = min(g * 128 + 2 * lane, (N - 2) & ~1);
    int k = 0;
    for (; k + 2 <= K; k += 2) {
        v2f w0[CHUNKS], w1[CHUNKS];
#pragma unroll
        for (int g = 0; g < CHUNKS; ++g) {
            w0[g] = *reinterpret_cast<const v2f*>(W + (size_t)(kW0 + k) * N + co[g]);
            w1[g] = *reinterpret_cast<const v2f*>(W + (size_t)(kW0 + k + 1) * N + co[g]);
        }
#pragma unroll
        for (int i = 0; i < 9; ++i) {
            v2f a2 = *reinterpret_cast<const v2f*>(A + (size_t)(rbase + i) * lda + k);
            v2f ax; ax.x = a2.x; ax.y = a2.x;
            v2f ay; ay.x = a2.y; ay.y = a2.y;
#pragma unroll
            for (int g = 0; g < CHUNKS; ++g) {
                acc[i][g] = __builtin_elementwise_fma(ax, w0[g], acc[i][g]);
                acc[i][g] = __builtin_elementwise_fma(ay, w1[g], acc[i][g]);
            }
        }
    }
    if (k < K) {                                  // odd K tail (emb: K=75)
        v2f w0[CHUNKS];
#pragma unroll
        for (int g = 0; g < CHUNKS; ++g)
            w0[g] = *reinterpret_cast<const v2f*>(W + (size_t)(kW0 + k) * N + co[g]);
#pragma unroll
        for (int i = 0; i < 9; ++i) {
            float a = A[(size_t)(rbase + i) * lda + k];
            v2f av; av.x = a; av.y = a;
#pragma unroll
            for (int g = 0; g < CHUNKS; ++g)
                acc[i][g] = __builtin_elementwise_fma(av, w0[g], acc[i][g]);
        }
    }
}

// -------- spmm (float4 cols, global source, N=256) --------------------------
__device__ __forceinline__ void spmm_row4(
    const float* __restrict__ tb,            // global, stride 256
    const float* __restrict__ bias,
    const float2* __restrict__ pb, int2 cc,
    float* __restrict__ yrow, int lane)
{
    const int c4 = 4 * lane;
    const float4* pq = reinterpret_cast<const float4*>(pb);
    v4f acc[4];
#pragma unroll
    for (int h = 0; h < 4; ++h) { acc[h].x = 0.f; acc[h].y = 0.f; acc[h].z = 0.f; acc[h].w = 0.f; }
    int q = 0;
    for (; q + 4 <= cc.x; q += 4) {
        float4 p0 = pq[q >> 1], p1 = pq[(q >> 1) + 1];
        float w[4]; int j[4];
        w[0] = p0.x; j[0] = __float_as_int(p0.y);
        w[1] = p0.z; j[1] = __float_as_int(p0.w);
        w[2] = p1.x; j[2] = __float_as_int(p1.y);
        w[3] = p1.z; j[3] = __float_as_int(p1.w);
#pragma unroll
        for (int h = 0; h < 4; ++h) {
            v4f r4 = *reinterpret_cast<const v4f*>(tb + (size_t)j[h] * 256 + c4);
            v4f wv; wv.x = w[h]; wv.y = w[h]; wv.z = w[h]; wv.w = w[h];
            acc[h] = __builtin_elementwise_fma(wv, r4, acc[h]);
        }
    }
    for (; q < cc.x; ++q) {
        float2 f = pb[q];
        v4f r4 = *reinterpret_cast<const v4f*>(tb + (size_t)__float_as_int(f.y) * 256 + c4);
        v4f wv; wv.x = f.x; wv.y = f.x; wv.z = f.x; wv.w = f.x;
        acc[0] = __builtin_elementwise_fma(wv, r4, acc[0]);
    }
    for (int v = 0; v < cc.y; ++v) {
        float2 f = pb[(NPAIR - 1) - v];
        v4f r4 = *reinterpret_cast<const v4f*>(tb + (size_t)__float_as_int(f.y) * 256 + c4);
        v4f wv; wv.x = f.x; wv.y = f.x; wv.z = f.x; wv.w = f.x;
        acc[0] = __builtin_elementwise_fma(wv, r4, acc[0]);
    }
    v4f s = (acc[0] + acc[1]) + (acc[2] + acc[3]);
    v4f bv = *reinterpret_cast<const v4f*>(bias + c4);
    s = s + bv;
    s.x = fmaxf(s.x, 0.f); s.y = fmaxf(s.y, 0.f);
    s.z = fmaxf(s.z, 0.f); s.w = fmaxf(s.w, 0.f);
    *reinterpret_cast<v4f*>(yrow + c4) = s;
}

// -------- pool (float4 cols, global source, N=256) --------------------------
__device__ __forceinline__ void pool_row4(
    const float* __restrict__ yb,
    const float2* __restrict__ pb, int cx,
    float* __restrict__ prow, int lane)
{
    const int c4 = 4 * lane;
    const float4* pq = reinterpret_cast<const float4*>(pb);
    v4f m[4];
#pragma unroll
    for (int h = 0; h < 4; ++h) { m[h].x = 0.f; m[h].y = 0.f; m[h].z = 0.f; m[h].w = 0.f; }
    int q = 0;
    for (; q + 4 <= cx; q += 4) {
        float4 p0 = pq[q >> 1], p1 = pq[(q >> 1) + 1];
        int j[4];
        j[0] = __float_as_int(p0.y); j[1] = __float_as_int(p0.w);
        j[2] = __float_as_int(p1.y); j[3] = __float_as_int(p1.w);
#pragma unroll
        for (int h = 0; h < 4; ++h) {
            v4f r4 = *reinterpret_cast<const v4f*>(yb + (size_t)j[h] * 256 + c4);
            m[h].x = fmaxf(m[h].x, r4.x); m[h].y = fmaxf(m[h].y, r4.y);
            m[h].z = fmaxf(m[h].z, r4.z); m[h].w = fmaxf(m[h].w, r4.w);
        }
    }
    for (; q < cx; ++q) {
        v4f r4 = *reinterpret_cast<const v4f*>(yb + (size_t)__float_as_int(pb[q].y) * 256 + c4);
        m[0].x = fmaxf(m[0].x, r4.x); m[0].y = fmaxf(m[0].y, r4.y);
        m[0].z = fmaxf(m[0].z, r4.z); m[0].w = fmaxf(m[0].w, r4.w);
    }
    v4f s;
    s.x = fmaxf(fmaxf(m[0].x, m[1].x), fmaxf(m[2].x, m[3].x));
    s.y = fmaxf(fmaxf(m[0].y, m[1].y), fmaxf(m[2].y, m[3].y));
    s.z = fmaxf(fmaxf(m[0].z, m[1].z), fmaxf(m[2].z, m[3].z));
    s.w = fmaxf(fmaxf(m[0].w, m[1].w), fmaxf(m[2].w, m[3].w));
    *reinterpret_cast<v4f*>(prow + c4) = s;
}

// -------- spmm (float2 cols, LDS source) ------------------------------------
__device__ __forceinline__ void spmm_row2(
    const float* __restrict__ tb, int ldt, int scmax,   // LDS
    const float* __restrict__ bias, int N,
    const float2* __restrict__ pb, int2 cc,
    float* __restrict__ yrow, int lane)
{
    const int c0 = 2 * lane;
    const int sc = min(c0, scmax);
    const float4* pq = reinterpret_cast<const float4*>(pb);
    v2f acc[4];
#pragma unroll
    for (int h = 0; h < 4; ++h) { acc[h].x = 0.f; acc[h].y = 0.f; }
    int q = 0;
    for (; q + 4 <= cc.x; q += 4) {
        float4 p0 = pq[q >> 1], p1 = pq[(q >> 1) + 1];
        float w[4]; int j[4];
        w[0] = p0.x; j[0] = __float_as_int(p0.y);
        w[1] = p0.z; j[1] = __float_as_int(p0.w);
        w[2] = p1.x; j[2] = __float_as_int(p1.y);
        w[3] = p1.z; j[3] = __float_as_int(p1.w);
#pragma unroll
        for (int h = 0; h < 4; ++h) {
            v2f r2 = *reinterpret_cast<const v2f*>(tb + (size_t)j[h] * ldt + sc);
            v2f wv; wv.x = w[h]; wv.y = w[h];
            acc[h] = __builtin_elementwise_fma(wv, r2, acc[h]);
        }
    }
    for (; q < cc.x; ++q) {
        float2 f = pb[q];
        v2f r2 = *reinterpret_cast<const v2f*>(tb + (size_t)__float_as_int(f.y) * ldt + sc);
        v2f wv; wv.x = f.x; wv.y = f.x;
        acc[0] = __builtin_elementwise_fma(wv, r2, acc[0]);
    }
    for (int v = 0; v < cc.y; ++v) {
        float2 f = pb[(NPAIR - 1) - v];
        v2f r2 = *reinterpret_cast<const v2f*>(tb + (size_t)__float_as_int(f.y) * ldt + sc);
        v2f wv; wv.x = f.x; wv.y = f.x;
        acc[0] = __builtin_elementwise_fma(wv, r2, acc[0]);
    }
    v2f s = (acc[0] + acc[1]) + (acc[2] + acc[3]);
    float b0 = bias[min(c0, N - 1)];
    float b1 = (c0 + 1 < N) ? bias[c0 + 1] : 0.f;
    s.x = fmaxf(s.x + b0, 0.f);
    s.y = fmaxf(s.y + b1, 0.f);
    if (c0 < N) {
        v2f o; o.x = s.x; o.y = (c0 + 1 < N) ? s.y : 0.f;
        *reinterpret_cast<v2f*>(yrow + c0) = o;
    }
}

// -------- pool (float2 cols, LDS source) ------------------------------------
__device__ __forceinline__ void pool_row2(
    const float* __restrict__ yb, int ldt, int scmax, int N,
    const float2* __restrict__ pb, int cx,
    float* __restrict__ prow, int lane)
{
    const int c0 = 2 * lane;
    const int sc = min(c0, scmax);
    const float4* pq = reinterpret_cast<const float4*>(pb);
    v2f m[4];
#pragma unroll
    for (int h = 0; h < 4; ++h) { m[h].x = 0.f; m[h].y = 0.f; }
    int q = 0;
    for (; q + 4 <= cx; q += 4) {
        float4 p0 = pq[q >> 1], p1 = pq[(q >> 1) + 1];
        int j[4];
        j[0] = __float_as_int(p0.y); j[1] = __float_as_int(p0.w);
        j[2] = __float_as_int(p1.y); j[3] = __float_as_int(p1.w);
#pragma unroll
        for (int h = 0; h < 4; ++h) {
            v2f r2 = *reinterpret_cast<const v2f*>(yb + (size_t)j[h] * ldt + sc);
            m[h].x = fmaxf(m[h].x, r2.x); m[h].y = fmaxf(m[h].y, r2.y);
        }
    }
    for (; q < cx; ++q) {
        v2f r2 = *reinterpret_cast<const v2f*>(yb + (size_t)__float_as_int(pb[q].y) * ldt + sc);
        m[0].x = fmaxf(m[0].x, r2.x); m[0].y = fmaxf(m[0].y, r2.y);
    }
    v2f s;
    s.x = fmaxf(fmaxf(m[0].x, m[1].x), fmaxf(m[2].x, m[3].x));
    s.y = fmaxf(fmaxf(m[0].y, m[1].y), fmaxf(m[2].y, m[3].y));
    if (c0 < N) {
        v2f o; o.x = s.x; o.y = (c0 + 1 < N) ? s.y : 0.f;
        *reinterpret_cast<v2f*>(prow + c0) = o;
    }
}

// -------- t4: t4S[r] = dot(pool3(y3)[r,0:75], gc4_w) ------------------------
__device__ __forceinline__ void t4_row_l(
    const float* __restrict__ yb,            // y3 global, stride 76
    const float2* __restrict__ pb, int cx,
    const float* __restrict__ gc4_w,
    float* __restrict__ t4S, int r, int lane)
{
    const float4* pq = reinterpret_cast<const float4*>(pb);
    const float gw0 = gc4_w[lane];
    const float gw1 = (lane < 11) ? gc4_w[64 + lane] : 0.f;
    const int c2 = 64 + min(lane, 10);

    float m0a = 0.f, m1a = 0.f, m0b = 0.f, m1b = 0.f;
    float m0c = 0.f, m1c = 0.f, m0d = 0.f, m1d = 0.f;
    int q = 0;
    for (; q + 4 <= cx; q += 4) {
        float4 pA = pq[q >> 1], pB = pq[(q >> 1) + 1];
        const float* r0 = yb + (size_t)__float_as_int(pA.y) * 76;
        const float* r1 = yb + (size_t)__float_as_int(pA.w) * 76;
        const float* r2 = yb + (size_t)__float_as_int(pB.y) * 76;
        const float* r3 = yb + (size_t)__float_as_int(pB.w) * 76;
        m0a = fmaxf(m0a, r0[lane]); m1a = fmaxf(m1a, r0[c2]);
        m0b = fmaxf(m0b, r1[lane]); m1b = fmaxf(m1b, r1[c2]);
        m0c = fmaxf(m0c, r2[lane]); m1c = fmaxf(m1c, r2[c2]);
        m0d = fmaxf(m0d, r3[lane]); m1d = fmaxf(m1d, r3[c2]);
    }
    for (; q < cx; ++q) {
        const float* r0 = yb + (size_t)__float_as_int(pb[q].y) * 76;
        m0a = fmaxf(m0a, r0[lane]); m1a = fmaxf(m1a, r0[c2]);
    }
    float m0 = fmaxf(fmaxf(m0a, m0b), fmaxf(m0c, m0d));
    float m1 = fmaxf(fmaxf(m1a, m1b), fmaxf(m1c, m1d));
    float v = m0 * gw0 + m1 * gw1;
#pragma unroll
    for (int off = 32; off; off >>= 1) v += __shfl_xor(v, off, 64);
    if (lane == 0) t4S[r] = v;
}

// --------------------------- one block = one graph --------------------------
__global__ __launch_bounds__(1024, 1)
void graph_k(Params P)
{
    __shared__ __align__(16) float SCR[20216];           // 80.9 KB scratch
    __shared__ __align__(16) float2 pairsS[NN][NPAIR];   // 68.1 KB
    __shared__ int2  cS[NN];
    __shared__ float t4S[NN];
    __shared__ float y4S[NN];
    __shared__ float rS[3];

    const int b    = blockIdx.x;
    const int tid  = threadIdx.x;
    const int wave = tid >> 6, lane = tid & 63;
    const int rbase = (wave * NN) >> 4;
    const int rcnt  = (((wave + 1) * NN) >> 4) - rbase;   // 8 or 9

    float* bAg = P.bA + (size_t)b * NN * 256;
    float* bBg = P.bB + (size_t)b * NN * 256;
    float* bCg = P.bC + (size_t)b * NN * 256;

    // S0: x -> SCR (stride 76, col75 zero-pad) + ballot prep -> LDS
    for (int i = tid; i < NN * 76; i += 1024) {
        int r = i / 76, c = i - r * 76;
        SCR[i] = (c < 75) ? P.x[((size_t)b * NN + r) * 75 + c] : 0.f;
    }
    for (int r = wave; r < NN; r += NW)
        prep_row_l(P.adj + ((size_t)b * NN + r) * NN, pairsS[r], cS, r, lane);
    __syncthreads();

    // S0b: emb = relu(x @ emb_w + b); h0 -> SCR (stride 152)
    {
        v2f acc[9][2];
#pragma unroll
        for (int i = 0; i < 9; ++i)
#pragma unroll
            for (int g = 0; g < 2; ++g) { acc[i][g].x = 0.f; acc[i][g].y = 0.f; }
        gemm_acc<2>(SCR, 76, 75, 0, P.emb_w, 150, acc, rbase, lane);
        __syncthreads();                      // all x reads done
#pragma unroll
        for (int i = 0; i < 9; ++i) {
            if (i < rcnt) {
#pragma unroll
                for (int g = 0; g < 2; ++g) {
                    int c = g * 128 + 2 * lane;
                    if (c < 150) {
                        v2f bv = *reinterpret_cast<const v2f*>(P.emb_b + c);
                        v2f v = acc[i][g] + bv;
                        v.x = fmaxf(v.x, 0.f); v.y = fmaxf(v.y, 0.f);
                        *reinterpret_cast<v2f*>(SCR + (size_t)(rbase + i) * 152 + c) = v;
                    }
                }
            }
        }
        __syncthreads();
    }
    // S1: t1 = h0 @ gc1_w -> bA (stride 256)
    {
        v2f acc[9][2];
#pragma unroll
        for (int i = 0; i < 9; ++i)
#pragma unroll
            for (int g = 0; g < 2; ++g) { acc[i][g].x = 0.f; acc[i][g].y = 0.f; }
        gemm_acc<2>(SCR, 152, 150, 0, P.gc1_w, 256, acc, rbase, lane);
#pragma unroll
        for (int i = 0; i < 9; ++i) {
            if (i < rcnt) {
#pragma unroll
                for (int g = 0; g < 2; ++g) {
                    int c = g * 128 + 2 * lane;
                    *reinterpret_cast<v2f*>(bAg + (size_t)(rbase + i) * 256 + c) = acc[i][g];
                }
            }
        }
    }
    __syncthreads();
    // S2: y1 = relu(spmm(t1)+b1) -> bB (stride 256)
    for (int r = wave; r < NN; r += NW)
        spmm_row4(bAg, P.gc1_b, pairsS[r], cS[r], bBg + (size_t)r * 256, lane);
    __syncthreads();
    // S3: p1 = pool(y1) -> bC (stride 256)
    for (int r = wave; r < NN; r += NW)
        pool_row4(bBg, pairsS[r], cS[r].x, bCg + (size_t)r * 256, lane);
    __syncthreads();
    // S4: t2 = p1 @ gc2_w (two 128-col k-passes via SCR) -> SCR (stride 130)
    {
        v2f acc[9][1];
#pragma unroll
        for (int i = 0; i < 9; ++i) { acc[i][0].x = 0.f; acc[i][0].y = 0.f; }
        for (int kp = 0; kp < 2; ++kp) {
            for (int i = tid; i < NN * 128; i += 1024) {
                int r = i >> 7, c = i & 127;
                SCR[r * 130 + c] = bCg[(size_t)r * 256 + kp * 128 + c];
            }
            __syncthreads();
            gemm_acc<1>(SCR, 130, 128, kp * 128, P.gc2_w, 128, acc, rbase, lane);
            __syncthreads();                  // SCR reads done before overwrite
        }
#pragma unroll
        for (int i = 0; i < 9; ++i) {
            if (i < rcnt)
                *reinterpret_cast<v2f*>(SCR + (size_t)(rbase + i) * 130 + 2 * lane) = acc[i][0];
        }
        __syncthreads();
    }
    // S5: y2 = relu(spmm(t2 LDS)+b2) -> bB (stride 128)
    for (int r = wave; r < NN; r += NW)
        spmm_row2(SCR, 130, 126, P.gc2_b, 128, pairsS[r], cS[r],
                  bBg + (size_t)r * 128, lane);
    __syncthreads();
    // S6: stage y2 -> SCR(130); p2 = pool(y2 LDS) -> bC (stride 128)
    for (int i = tid; i < NN * 128; i += 1024) {
        int r = i >> 7, c = i & 127;
        SCR[r * 130 + c] = bBg[i];
    }
    __syncthreads();
    for (int r = wave; r < NN; r += NW)
        pool_row2(SCR, 130, 126, 128, pairsS[r], cS[r].x,
                  bCg + (size_t)r * 128, lane);
    __syncthreads();
    // S7: stage p2 -> SCR(130); t3 = p2 @ gc3_w -> SCR (stride 78, N=75)
    for (int i = tid; i < NN * 128; i += 1024) {
        int r = i >> 7, c = i & 127;
        SCR[r * 130 + c] = bCg[i];
    }
    __syncthreads();
    {
        v2f acc3[9];
#pragma unroll
        for (int i = 0; i < 9; ++i) { acc3[i].x = 0.f; acc3[i].y = 0.f; }
        const int c0 = 2 * lane;
        const int cw0 = min(c0, 74), cw1 = min(c0 + 1, 74);
        for (int k = 0; k < 128; k += 2) {
            v2f w0, w1;
            w0.x = P.gc3_w[(size_t)k * 75 + cw0];
            w0.y = P.gc3_w[(size_t)k * 75 + cw1];
            w1.x = P.gc3_w[(size_t)(k + 1) * 75 + cw0];
            w1.y = P.gc3_w[(size_t)(k + 1) * 75 + cw1];
#pragma unroll
            for (int i = 0; i < 9; ++i) {
                v2f a2 = *reinterpret_cast<const v2f*>(SCR + (size_t)(rbase + i) * 130 + k);
                v2f ax; ax.x = a2.x; ax.y = a2.x;
                v2f ay; ay.x = a2.y; ay.y = a2.y;
                acc3[i] = __builtin_elementwise_fma(ax, w0, acc3[i]);
                acc3[i] = __builtin_elementwise_fma(ay, w1, acc3[i]);
            }
        }
        __syncthreads();                      // p2 reads done
#pragma unroll
        for (int i = 0; i < 9; ++i) {
            if (i < rcnt && c0 < 75) {
                v2f o; o.x = acc3[i].x;
                o.y = (c0 + 1 < 75) ? acc3[i].y : 0.f;
                *reinterpret_cast<v2f*>(SCR + (size_t)(rbase + i) * 78 + c0) = o;
            }
        }
        __syncthreads();
    }
    // S8: y3 = relu(spmm(t3 LDS)+b3) -> bB (stride 76, N=75)
    for (int r = wave; r < NN; r += NW)
        spmm_row2(SCR, 78, 74, P.gc3_b, 75, pairsS[r], cS[r],
                  bBg + (size_t)r * 76, lane);
    __syncthreads();
    // S9: t4S[r] = pool3(y3)[r] . gc4_w
    for (int r = wave; r < NN; r += NW)
        t4_row_l(bBg, pairsS[r], cS[r].x, P.gc4_w, t4S, r, lane);
    __syncthreads();
    // S10: tail — y4 = relu(A@t4+b4); fc1; fin; sigmoid
    if (tid < NN) {
        const float2* pb = pairsS[tid];
        int2 c = cS[tid];
        float s = P.gc4_b[0];
        for (int q = 0; q < c.x; ++q) {
            float2 f = pb[q];
            s = fmaf(f.x, t4S[__float_as_int(f.y)], s);
        }
        for (int q = 0; q < c.y; ++q) {
            float2 f = pb[(NPAIR - 1) - q];
            s = fmaf(f.x, t4S[__float_as_int(f.y)], s);
        }
        y4S[tid] = fmaxf(s, 0.f);
    }
    __syncthreads();
    if (tid < 3) {
        float s = P.fc1_b[tid];
        for (int j = 0; j < 132; ++j)
            s = fmaf(y4S[1 + j], P.fc1_w[j * 3 + tid], s);
        rS[tid] = s;
    }
    __syncthreads();
    if (tid == 0) {
        float z = P.fin_b[0] + y4S[0] * P.fin_w[0] + rS[0] * P.fin_w[1]
                + rS[1] * P.fin_w[2] + rS[2] * P.fin_w[3];
        P.out[b] = 1.f / (1.f + expf(-z));
    }
}

extern "C" void kernel_launch(void* const* d_in, const int* in_sizes, int n_in,
                              void* d_out, int out_size, void* d_ws, size_t ws_size,
                              hipStream_t stream)
{
    const size_t MR = (size_t)64 * NN;           // 8512 rows
    float* bA = (float*)d_ws;
    float* bB = bA + MR * 256;
    float* bC = bB + MR * 256;

    Params hp;
    hp.x     = (const float*)d_in[0];
    hp.adj   = (const float*)d_in[1];
    hp.emb_w = (const float*)d_in[2];
    hp.emb_b = (const float*)d_in[3];
    hp.gc1_w = (const float*)d_in[4];
    hp.gc1_b = (const float*)d_in[5];
    hp.gc2_w = (const float*)d_in[6];
    hp.gc2_b = (const float*)d_in[7];
    hp.gc3_w = (const float*)d_in[8];
    hp.gc3_b = (const float*)d_in[9];
    hp.gc4_w = (const float*)d_in[10];
    hp.gc4_b = (const float*)d_in[11];
    hp.fc1_w = (const float*)d_in[12];
    hp.fc1_b = (const float*)d_in[13];
    hp.fin_w = (const float*)d_in[14];
    hp.fin_b = (const float*)d_in[15];
    hp.bA = bA; hp.bB = bB; hp.bC = bC;
    hp.out = (float*)d_out;

    hipLaunchKernelGGL(graph_k, dim3(64), dim3(1024), 0, stream, hp);
}